// Round 3
// baseline (244.082 us; speedup 1.0000x reference)
//
#include <hip/hip_runtime.h>
#include <cmath>
#include <cstdint>

// Instant-NGP hash-grid encoder, level-phased for L2 residency + x-pair float4 gathers.
// B=524288 points, L=16 levels, F=2. Fast-level tables are 4MB (= per-XCD L2).
//
// Kernel A (gather): grid (B/256, 16), blockIdx.y = level -> concurrently resident
//   blocks share 1-2 levels -> each XCD L2 holds the live table. Writes ws[l][b].
//   Corner pairs along x differ by +1 (dense) / ^1 (fast, even ix) in table index,
//   so each pair is served by 16B-aligned float4 loads: 1 always + 1 exec-masked.
// Kernel B (transpose): ws[l][b] -> out[b*16+l] via LDS tiles.

#define NLEVELS 16
#define BPOINTS 524288

struct LevelMeta {
    float    scale[NLEVELS];
    uint32_t size[NLEVELS];     // entries
    uint32_t offset[NLEVELS];   // float2 units (always multiple of 8)
    uint32_t mul_y[NLEVELS];    // dense: r    ; fast: 2654435761
    uint32_t mul_z[NLEVELS];    // dense: r*r  ; fast: 805459861
    uint32_t fast[NLEVELS];
};

__device__ __forceinline__ void encode_pairs(
    const float*  __restrict__ pos,
    const float4* __restrict__ tbl4,   // table viewed as 2-entry blocks
    int b, int l, const LevelMeta& meta, float& o0, float& o1)
{
    const float x = pos[b * 3 + 0];
    const float y = pos[b * 3 + 1];
    const float z = pos[b * 3 + 2];

    const float s = meta.scale[l];
    const float px = __fadd_rn(__fmul_rn(x, s), 0.5f);
    const float py = __fadd_rn(__fmul_rn(y, s), 0.5f);
    const float pz = __fadd_rn(__fmul_rn(z, s), 0.5f);

    const float gx = floorf(px), gy = floorf(py), gz = floorf(pz);
    const float fx = px - gx,    fy = py - gy,    fz = pz - gz;

    const uint32_t ix = (uint32_t)gx, iy = (uint32_t)gy, iz = (uint32_t)gz;

    const uint32_t size  = meta.size[l];
    const uint32_t off2  = meta.offset[l] >> 1;   // float4 units
    const uint32_t my    = meta.mul_y[l];
    const uint32_t mz    = meta.mul_z[l];
    const bool     fastl = meta.fast[l] != 0;     // block-uniform (l = blockIdx.y)
    const uint32_t mask  = size - 1u;             // fast levels: size == 2^19

    const uint32_t hy0 = iy * my, hy1 = hy0 + my;
    const uint32_t hz0 = iz * mz, hz1 = hz0 + mz;

    // 4 pairs, p = zo*2+yo; corner0 has x=ix, corner1 has x=ix+1.
    uint32_t blk0[4], blk1[4], par0[4], par1[4];
#pragma unroll
    for (int p = 0; p < 4; ++p) {
        const uint32_t hy = (p & 1) ? hy1 : hy0;
        const uint32_t hz = (p & 2) ? hz1 : hz0;
        uint32_t h0, h1;
        if (fastl) {
            const uint32_t r = hy ^ hz;
            h0 = (ix ^ r) & mask;
            h1 = ((ix + 1u) ^ r) & mask;
        } else {
            const uint32_t t0 = ix + hy + hz;       // < 2*size (r+r^2+r^3 < 2r^3)
            h0 = (t0 >= size) ? (t0 - size) : t0;
            const uint32_t t1 = t0 + 1u;
            h1 = (t1 >= size) ? (t1 - size) : t1;
        }
        blk0[p] = h0 >> 1;  par0[p] = h0 & 1u;
        blk1[p] = h1 >> 1;  par1[p] = h1 & 1u;
    }

    // Issue the 4 unconditional pair loads, then the exec-masked second loads.
    float4 fa[4], fb[4];
#pragma unroll
    for (int p = 0; p < 4; ++p) fa[p] = tbl4[off2 + blk0[p]];
#pragma unroll
    for (int p = 0; p < 4; ++p) {
        float4 t = fa[p];
        if (blk1[p] != blk0[p]) t = tbl4[off2 + blk1[p]];
        fb[p] = t;
    }

    const float wx0 = 1.0f - fx, wx1 = fx;
    const float wy0 = 1.0f - fy, wy1 = fy;
    const float wz0 = 1.0f - fz, wz1 = fz;

    // Accumulate in reference corner order: x fastest, then y, then z.
    o0 = 0.0f; o1 = 0.0f;
#pragma unroll
    for (int p = 0; p < 4; ++p) {
        const float wyz = __fmul_rn((p & 1) ? wy1 : wy0, 1.0f) ;
        const float wyv = (p & 1) ? wy1 : wy0;
        const float wzv = (p & 2) ? wz1 : wz0;

        const float w0 = __fmul_rn(__fmul_rn(wx0, wyv), wzv);
        const float f0x = par0[p] ? fa[p].z : fa[p].x;
        const float f0y = par0[p] ? fa[p].w : fa[p].y;
        o0 = __fmaf_rn(w0, f0x, o0);
        o1 = __fmaf_rn(w0, f0y, o1);

        const float w1 = __fmul_rn(__fmul_rn(wx1, wyv), wzv);
        const float f1x = par1[p] ? fb[p].z : fb[p].x;
        const float f1y = par1[p] ? fb[p].w : fb[p].y;
        o0 = __fmaf_rn(w1, f1x, o0);
        o1 = __fmaf_rn(w1, f1y, o1);
        (void)wyz;
    }
}

// ---- Kernel A: phased gather, level-major ws output ----
__global__ __launch_bounds__(256) void hashenc_gather(
    const float*  __restrict__ pos,
    const float4* __restrict__ tbl4,
    float2*       __restrict__ ws,
    LevelMeta meta)
{
    const int l = blockIdx.y;                       // wave-uniform level -> SGPR meta
    const int b = blockIdx.x * 256 + threadIdx.x;
    float o0, o1;
    encode_pairs(pos, tbl4, b, l, meta, o0, o1);
    ws[l * BPOINTS + b] = make_float2(o0, o1);      // coalesced
}

// ---- Kernel B: transpose ws[l][b] -> out[b*16+l], LDS 16x64 tiles ----
__global__ __launch_bounds__(256) void hashenc_transpose(
    const float2* __restrict__ ws,
    float2*       __restrict__ out)
{
    __shared__ float2 tile[NLEVELS][65];            // +1 pad breaks bank conflicts
    const int b0  = blockIdx.x * 64;
    const int tid = threadIdx.x;

#pragma unroll
    for (int k = 0; k < 4; ++k) {
        const int idx = k * 256 + tid;              // [0,1024)
        const int l = idx >> 6, j = idx & 63;
        tile[l][j] = ws[l * BPOINTS + b0 + j];      // 512B/row coalesced
    }
    __syncthreads();
#pragma unroll
    for (int k = 0; k < 4; ++k) {
        const int idx = k * 256 + tid;              // flat out index within tile
        const int j = idx >> 4, l = idx & 15;
        union { float2 f2; unsigned long long u64; } u;
        u.f2 = tile[l][j];
        __builtin_nontemporal_store(u.u64,
            (unsigned long long*)&out[b0 * NLEVELS + idx]);  // 2KB contiguous
    }
}

// ---- Fallback (point-major, direct write) if workspace too small ----
__global__ __launch_bounds__(256) void hashenc_direct(
    const float*  __restrict__ pos,
    const float4* __restrict__ tbl4,
    float2*       __restrict__ out,
    LevelMeta meta)
{
    const int t = blockIdx.x * 256 + threadIdx.x;
    const int b = t >> 4;
    const int l = t & 15;
    float o0, o1;
    encode_pairs(pos, tbl4, b, l, meta, o0, o1);
    union { float2 f2; unsigned long long u64; } u;
    u.f2 = make_float2(o0, o1);
    __builtin_nontemporal_store(u.u64, (unsigned long long*)&out[t]);
}

static void fill_meta(LevelMeta& m)
{
    const double PLS = 1.3195079565048218;
    const uint32_t P1 = 2654435761u, P2 = 805459861u;
    const long long MAXP = 1ll << 19;
    long long off = 0;
    for (int i = 0; i < NLEVELS; ++i) {
        const double scale_d = 16.0 * pow(PLS, (double)i) - 1.0;
        const long long r = (long long)ceil(scale_d) + 1;
        const long long full = r * r * r;
        const long long aligned = ((full + 7) / 8) * 8;
        const long long p = aligned < MAXP ? aligned : MAXP;
        const bool fast = full > p;
        m.scale[i]  = (float)scale_d;
        m.size[i]   = (uint32_t)p;
        m.offset[i] = (uint32_t)off;
        m.mul_y[i]  = fast ? P1 : (uint32_t)r;
        m.mul_z[i]  = fast ? P2 : (uint32_t)(r * r);
        m.fast[i]   = fast ? 1u : 0u;
        off += p;
    }
}

extern "C" void kernel_launch(void* const* d_in, const int* in_sizes, int n_in,
                              void* d_out, int out_size, void* d_ws, size_t ws_size,
                              hipStream_t stream)
{
    const float*  positions = (const float*)d_in[0];
    const float4* table4    = (const float4*)d_in[1];
    float2*       out       = (float2*)d_out;

    LevelMeta m;
    fill_meta(m);

    const size_t ws_need = (size_t)BPOINTS * NLEVELS * sizeof(float2);  // 64 MB
    if (ws_size >= ws_need) {
        dim3 grid(BPOINTS / 256, NLEVELS);
        hashenc_gather<<<grid, 256, 0, stream>>>(positions, table4, (float2*)d_ws, m);
        hashenc_transpose<<<BPOINTS / 64, 256, 0, stream>>>((const float2*)d_ws, out);
    } else {
        hashenc_direct<<<(BPOINTS * NLEVELS) / 256, 256, 0, stream>>>(positions, table4, out, m);
    }
}

// Round 4
// 236.039 us; speedup vs baseline: 1.0341x; 1.0341x over previous
//
#include <hip/hip_runtime.h>
#include <cmath>
#include <cstdint>

// Instant-NGP hash-grid encoder, level-phased for L2 residency.
// R4: revert to 8B gathers (R2 core), 2 points/thread for 16-deep gather MLP,
//     dense/fast levels split into two dispatches for rocprof attribution.
//
// Kernel A (gather2): grid (B/512, nlev), blockIdx.y+lbase = level.
//   Each thread: points 2t, 2t+1 at one level. All 16 gathers issued before
//   any consumption. Writes ws[l*B + b] as one float4 (coalesced).
// Kernel B (transpose): ws[l][b] -> out[b*16+l] via LDS tiles.

#define NLEVELS 16
#define BPOINTS 524288

struct LevelMeta {
    float    scale[NLEVELS];
    uint32_t size[NLEVELS];     // entries
    uint32_t offset[NLEVELS];   // float2 units
    uint32_t mul_y[NLEVELS];    // dense: r    ; fast: 2654435761
    uint32_t mul_z[NLEVELS];    // dense: r*r  ; fast: 805459861
    uint32_t fast[NLEVELS];
};

struct PtCtx {
    uint32_t idx[8];
    float wx0, wx1, wy0, wy1, wz0, wz1;
};

__device__ __forceinline__ void prep(
    float x, float y, float z, int l, const LevelMeta& meta, PtCtx& c)
{
    const float s = meta.scale[l];
    const float px = __fadd_rn(__fmul_rn(x, s), 0.5f);
    const float py = __fadd_rn(__fmul_rn(y, s), 0.5f);
    const float pz = __fadd_rn(__fmul_rn(z, s), 0.5f);

    const float gx = floorf(px), gy = floorf(py), gz = floorf(pz);
    const float fx = px - gx,    fy = py - gy,    fz = pz - gz;

    const uint32_t ix = (uint32_t)gx, iy = (uint32_t)gy, iz = (uint32_t)gz;

    const uint32_t size  = meta.size[l];
    const uint32_t off   = meta.offset[l];
    const uint32_t my    = meta.mul_y[l];
    const uint32_t mz    = meta.mul_z[l];
    const bool     fastl = meta.fast[l] != 0;    // block-uniform
    const uint32_t mask  = size - 1u;            // fast: size == 2^19

    const uint32_t hx0 = ix,      hx1 = ix + 1u;
    const uint32_t hy0 = iy * my, hy1 = hy0 + my;
    const uint32_t hz0 = iz * mz, hz1 = hz0 + mz;

#pragma unroll
    for (int k = 0; k < 8; ++k) {
        const uint32_t hxv = (k & 1) ? hx1 : hx0;
        const uint32_t hyv = (k & 2) ? hy1 : hy0;
        const uint32_t hzv = (k & 4) ? hz1 : hz0;
        uint32_t h;
        if (fastl) {
            h = (hxv ^ hyv ^ hzv) & mask;
        } else {
            h = hxv + hyv + hzv;                 // < 2*size
            h = (h >= size) ? (h - size) : h;
        }
        c.idx[k] = off + h;
    }
    c.wx0 = 1.0f - fx; c.wx1 = fx;
    c.wy0 = 1.0f - fy; c.wy1 = fy;
    c.wz0 = 1.0f - fz; c.wz1 = fz;
}

__device__ __forceinline__ void accum(
    const PtCtx& c, const float2 f[8], float& o0, float& o1)
{
    o0 = 0.0f; o1 = 0.0f;
#pragma unroll
    for (int k = 0; k < 8; ++k) {
        const float wxv = (k & 1) ? c.wx1 : c.wx0;
        const float wyv = (k & 2) ? c.wy1 : c.wy0;
        const float wzv = (k & 4) ? c.wz1 : c.wz0;
        const float w = __fmul_rn(__fmul_rn(wxv, wyv), wzv);
        o0 = __fmaf_rn(w, f[k].x, o0);
        o1 = __fmaf_rn(w, f[k].y, o1);
    }
}

// ---- Kernel A: phased gather, 2 points/thread, level-major ws ----
__global__ __launch_bounds__(256) void hashenc_gather2(
    const float*  __restrict__ pos,
    const float2* __restrict__ tbl,
    float2*       __restrict__ ws,
    LevelMeta meta, int lbase)
{
    const int l = lbase + blockIdx.y;               // wave-uniform -> SGPR meta
    const int t = blockIdx.x * 256 + threadIdx.x;
    const int b0 = t * 2;

    // 24B contiguous pos load per thread as 3x float2 (8B aligned)
    const float2 q0 = *(const float2*)(pos + (size_t)b0 * 3 + 0);  // x0 y0
    const float2 q1 = *(const float2*)(pos + (size_t)b0 * 3 + 2);  // z0 x1
    const float2 q2 = *(const float2*)(pos + (size_t)b0 * 3 + 4);  // y1 z1

    PtCtx A, B;
    prep(q0.x, q0.y, q1.x, l, meta, A);
    prep(q1.y, q2.x, q2.y, l, meta, B);

    // 16 independent gathers, all issued before any use
    float2 fa[8], fb[8];
#pragma unroll
    for (int k = 0; k < 8; ++k) fa[k] = tbl[A.idx[k]];
#pragma unroll
    for (int k = 0; k < 8; ++k) fb[k] = tbl[B.idx[k]];

    float a0, a1, b0f, b1f;
    accum(A, fa, a0, a1);
    accum(B, fb, b0f, b1f);

    float4 o; o.x = a0; o.y = a1; o.z = b0f; o.w = b1f;
    *(float4*)(ws + (size_t)l * BPOINTS + b0) = o;  // 16B coalesced
}

// ---- Kernel B: transpose ws[l][b] -> out[b*16+l], LDS 16x64 tiles ----
__global__ __launch_bounds__(256) void hashenc_transpose(
    const float2* __restrict__ ws,
    float2*       __restrict__ out)
{
    __shared__ float2 tile[NLEVELS][65];            // +1 pad breaks bank conflicts
    const int b0  = blockIdx.x * 64;
    const int tid = threadIdx.x;

#pragma unroll
    for (int k = 0; k < 4; ++k) {
        const int idx = k * 256 + tid;              // [0,1024)
        const int l = idx >> 6, j = idx & 63;
        tile[l][j] = ws[(size_t)l * BPOINTS + b0 + j];
    }
    __syncthreads();
#pragma unroll
    for (int k = 0; k < 4; ++k) {
        const int idx = k * 256 + tid;
        const int j = idx >> 4, l = idx & 15;
        union { float2 f2; unsigned long long u64; } u;
        u.f2 = tile[l][j];
        __builtin_nontemporal_store(u.u64,
            (unsigned long long*)&out[(size_t)b0 * NLEVELS + idx]);
    }
}

// ---- Fallback (point-major, direct write) if workspace too small ----
__global__ __launch_bounds__(256) void hashenc_direct(
    const float*  __restrict__ pos,
    const float2* __restrict__ tbl,
    float2*       __restrict__ out,
    LevelMeta meta)
{
    const int t = blockIdx.x * 256 + threadIdx.x;
    const int b = t >> 4;
    const int l = t & 15;
    PtCtx A;
    prep(pos[b * 3 + 0], pos[b * 3 + 1], pos[b * 3 + 2], l, meta, A);
    float2 f[8];
#pragma unroll
    for (int k = 0; k < 8; ++k) f[k] = tbl[A.idx[k]];
    float o0, o1;
    accum(A, f, o0, o1);
    union { float2 f2; unsigned long long u64; } u;
    u.f2 = make_float2(o0, o1);
    __builtin_nontemporal_store(u.u64, (unsigned long long*)&out[t]);
}

static void fill_meta(LevelMeta& m)
{
    const double PLS = 1.3195079565048218;
    const uint32_t P1 = 2654435761u, P2 = 805459861u;
    const long long MAXP = 1ll << 19;
    long long off = 0;
    for (int i = 0; i < NLEVELS; ++i) {
        const double scale_d = 16.0 * pow(PLS, (double)i) - 1.0;
        const long long r = (long long)ceil(scale_d) + 1;
        const long long full = r * r * r;
        const long long aligned = ((full + 7) / 8) * 8;
        const long long p = aligned < MAXP ? aligned : MAXP;
        const bool fast = full > p;
        m.scale[i]  = (float)scale_d;
        m.size[i]   = (uint32_t)p;
        m.offset[i] = (uint32_t)off;
        m.mul_y[i]  = fast ? P1 : (uint32_t)r;
        m.mul_z[i]  = fast ? P2 : (uint32_t)(r * r);
        m.fast[i]   = fast ? 1u : 0u;
        off += p;
    }
}

extern "C" void kernel_launch(void* const* d_in, const int* in_sizes, int n_in,
                              void* d_out, int out_size, void* d_ws, size_t ws_size,
                              hipStream_t stream)
{
    const float*  positions = (const float*)d_in[0];
    const float2* table     = (const float2*)d_in[1];
    float2*       out       = (float2*)d_out;

    LevelMeta m;
    fill_meta(m);

    const size_t ws_need = (size_t)BPOINTS * NLEVELS * sizeof(float2);  // 64 MB
    if (ws_size >= ws_need) {
        // dense levels 0-5, then fast levels 6-15: separate dispatches for
        // rocprof attribution; phasing behavior identical (x walks fastest).
        dim3 gridD(BPOINTS / 512, 6);
        hashenc_gather2<<<gridD, 256, 0, stream>>>(positions, table, (float2*)d_ws, m, 0);
        dim3 gridF(BPOINTS / 512, 10);
        hashenc_gather2<<<gridF, 256, 0, stream>>>(positions, table, (float2*)d_ws, m, 6);
        hashenc_transpose<<<BPOINTS / 64, 256, 0, stream>>>((const float2*)d_ws, out);
    } else {
        hashenc_direct<<<(BPOINTS * NLEVELS) / 256, 256, 0, stream>>>(positions, table, out, m);
    }
}

// Round 5
// 213.366 us; speedup vs baseline: 1.1440x; 1.1063x over previous
//
#include <hip/hip_runtime.h>
#include <cmath>
#include <cstdint>

// Instant-NGP hash-grid encoder, level-phased for L2 residency.
// R5 = revert to the R2 configuration (best measured: 213.6 us total).
//
// Model (fits R1-R4 data): TCP L1-miss service ~2.4 cyc per 8B-sector miss,
// no cross-instruction merge; 8 sector-misses/point/level is irreducible.
// R3 (wider loads) and R4 (2pt MLP) both regressed as this model predicts.
//
// Kernel A (gather): grid (B/256, 16). blockIdx.y = level -> concurrently
//   resident blocks share 1-2 levels -> each XCD's 4MB L2 holds the live
//   level's table (fast tables are exactly 4MB). Writes ws[l*B+b] coalesced.
// Kernel B (transpose): ws[l][b] -> out[b*16+l] via LDS 16x64 tiles.

#define NLEVELS 16
#define BPOINTS 524288

struct LevelMeta {
    float    scale[NLEVELS];
    uint32_t size[NLEVELS];     // entries
    uint32_t offset[NLEVELS];   // float2 units
    uint32_t mul_y[NLEVELS];    // dense: r    ; fast: 2654435761
    uint32_t mul_z[NLEVELS];    // dense: r*r  ; fast: 805459861
    uint32_t fast[NLEVELS];
};

__device__ __forceinline__ void encode_one(
    const float* __restrict__ pos, const float2* __restrict__ tbl,
    int b, int l, const LevelMeta& meta, float& o0, float& o1)
{
    const float x = pos[b * 3 + 0];
    const float y = pos[b * 3 + 1];
    const float z = pos[b * 3 + 2];

    const float s = meta.scale[l];
    const float px = __fadd_rn(__fmul_rn(x, s), 0.5f);
    const float py = __fadd_rn(__fmul_rn(y, s), 0.5f);
    const float pz = __fadd_rn(__fmul_rn(z, s), 0.5f);

    const float gx = floorf(px), gy = floorf(py), gz = floorf(pz);
    const float fx = px - gx,    fy = py - gy,    fz = pz - gz;

    const uint32_t ix = (uint32_t)gx, iy = (uint32_t)gy, iz = (uint32_t)gz;

    const uint32_t size  = meta.size[l];
    const uint32_t off   = meta.offset[l];
    const uint32_t my    = meta.mul_y[l];
    const uint32_t mz    = meta.mul_z[l];
    const bool     fastl = meta.fast[l] != 0;    // block-uniform (l = blockIdx.y)
    const uint32_t mask  = size - 1u;            // fast levels: size == 2^19

    const uint32_t hx0 = ix,      hx1 = ix + 1u;
    const uint32_t hy0 = iy * my, hy1 = hy0 + my;
    const uint32_t hz0 = iz * mz, hz1 = hz0 + mz;

    const float wx0 = 1.0f - fx, wx1 = fx;
    const float wy0 = 1.0f - fy, wy1 = fy;
    const float wz0 = 1.0f - fz, wz1 = fz;

    uint32_t idx[8];
#pragma unroll
    for (int c = 0; c < 8; ++c) {
        const uint32_t hxv = (c & 1) ? hx1 : hx0;
        const uint32_t hyv = (c & 2) ? hy1 : hy0;
        const uint32_t hzv = (c & 4) ? hz1 : hz0;
        uint32_t h;
        if (fastl) {
            h = (hxv ^ hyv ^ hzv) & mask;
        } else {
            h = hxv + hyv + hzv;                 // < 2*size -> one conditional subtract
            h = (h >= size) ? (h - size) : h;
        }
        idx[c] = off + h;
    }

    // all 8 gathers in flight before any use
    float2 f[8];
#pragma unroll
    for (int c = 0; c < 8; ++c) f[c] = tbl[idx[c]];

    o0 = 0.0f; o1 = 0.0f;
#pragma unroll
    for (int c = 0; c < 8; ++c) {
        const float wxv = (c & 1) ? wx1 : wx0;
        const float wyv = (c & 2) ? wy1 : wy0;
        const float wzv = (c & 4) ? wz1 : wz0;
        const float w = __fmul_rn(__fmul_rn(wxv, wyv), wzv);  // jnp.prod order
        o0 = __fmaf_rn(w, f[c].x, o0);
        o1 = __fmaf_rn(w, f[c].y, o1);
    }
}

// ---- Kernel A: phased gather, level-major ws output ----
__global__ __launch_bounds__(256) void hashenc_gather(
    const float*  __restrict__ pos,
    const float2* __restrict__ tbl,
    float2*       __restrict__ ws,
    LevelMeta meta)
{
    const int l = blockIdx.y;                       // wave-uniform level -> SGPR meta
    const int b = blockIdx.x * 256 + threadIdx.x;
    float o0, o1;
    encode_one(pos, tbl, b, l, meta, o0, o1);
    ws[(size_t)l * BPOINTS + b] = make_float2(o0, o1);   // coalesced
}

// ---- Kernel B: transpose ws[l][b] -> out[b*16+l], LDS 16x64 tiles ----
__global__ __launch_bounds__(256) void hashenc_transpose(
    const float2* __restrict__ ws,
    float2*       __restrict__ out)
{
    __shared__ float2 tile[NLEVELS][65];            // +1 pad breaks bank conflicts
    const int b0  = blockIdx.x * 64;
    const int tid = threadIdx.x;

#pragma unroll
    for (int k = 0; k < 4; ++k) {
        const int idx = k * 256 + tid;              // [0,1024)
        const int l = idx >> 6, j = idx & 63;
        tile[l][j] = ws[(size_t)l * BPOINTS + b0 + j];   // 512B/row coalesced
    }
    __syncthreads();
#pragma unroll
    for (int k = 0; k < 4; ++k) {
        const int idx = k * 256 + tid;              // flat out index within tile
        const int j = idx >> 4, l = idx & 15;
        union { float2 f2; unsigned long long u64; } u;
        u.f2 = tile[l][j];
        __builtin_nontemporal_store(u.u64,
            (unsigned long long*)&out[(size_t)b0 * NLEVELS + idx]);  // 2KB contiguous
    }
}

// ---- Fallback (point-major, direct write) if workspace too small ----
__global__ __launch_bounds__(256) void hashenc_direct(
    const float*  __restrict__ pos,
    const float2* __restrict__ tbl,
    float2*       __restrict__ out,
    LevelMeta meta)
{
    const int t = blockIdx.x * 256 + threadIdx.x;
    const int b = t >> 4;
    const int l = t & 15;
    float o0, o1;
    encode_one(pos, tbl, b, l, meta, o0, o1);
    union { float2 f2; unsigned long long u64; } u;
    u.f2 = make_float2(o0, o1);
    __builtin_nontemporal_store(u.u64, (unsigned long long*)&out[t]);
}

static void fill_meta(LevelMeta& m)
{
    const double PLS = 1.3195079565048218;
    const uint32_t P1 = 2654435761u, P2 = 805459861u;
    const long long MAXP = 1ll << 19;
    long long off = 0;
    for (int i = 0; i < NLEVELS; ++i) {
        const double scale_d = 16.0 * pow(PLS, (double)i) - 1.0;
        const long long r = (long long)ceil(scale_d) + 1;
        const long long full = r * r * r;
        const long long aligned = ((full + 7) / 8) * 8;
        const long long p = aligned < MAXP ? aligned : MAXP;
        const bool fast = full > p;
        m.scale[i]  = (float)scale_d;
        m.size[i]   = (uint32_t)p;
        m.offset[i] = (uint32_t)off;
        m.mul_y[i]  = fast ? P1 : (uint32_t)r;
        m.mul_z[i]  = fast ? P2 : (uint32_t)(r * r);
        m.fast[i]   = fast ? 1u : 0u;
        off += p;
    }
}

extern "C" void kernel_launch(void* const* d_in, const int* in_sizes, int n_in,
                              void* d_out, int out_size, void* d_ws, size_t ws_size,
                              hipStream_t stream)
{
    const float*  positions = (const float*)d_in[0];
    const float2* table     = (const float2*)d_in[1];
    float2*       out       = (float2*)d_out;

    LevelMeta m;
    fill_meta(m);

    const size_t ws_need = (size_t)BPOINTS * NLEVELS * sizeof(float2);  // 64 MB
    if (ws_size >= ws_need) {
        dim3 grid(BPOINTS / 256, NLEVELS);
        hashenc_gather<<<grid, 256, 0, stream>>>(positions, table, (float2*)d_ws, m);
        hashenc_transpose<<<BPOINTS / 64, 256, 0, stream>>>((const float2*)d_ws, out);
    } else {
        hashenc_direct<<<(BPOINTS * NLEVELS) / 256, 256, 0, stream>>>(positions, table, out, m);
    }
}